// Round 9
// baseline (792.420 us; speedup 1.0000x reference)
//
#include <hip/hip_runtime.h>
#include <math.h>

#define BB 16
#define NN 4096

typedef float v2f __attribute__((ext_vector_type(2)));
typedef short bfrag8 __attribute__((ext_vector_type(8)));   // 8 bf16 (4 VGPR) MFMA A/B frag
typedef float fx4 __attribute__((ext_vector_type(4)));      // MFMA C/D frag

__device__ __forceinline__ v2f pkfma(v2f a, v2f b, v2f c) {
    return __builtin_elementwise_fma(a, b, c);   // -> v_pk_fma_f32 on gfx950
}

__device__ __forceinline__ fx4 mfma16(bfrag8 a, bfrag8 b, fx4 c) {
    return __builtin_amdgcn_mfma_f32_16x16x32_bf16(a, b, c, 0, 0, 0);
}

// round-to-nearest-even fp32 -> bf16 bits (no NaN handling needed here)
__device__ __forceinline__ unsigned short bf16rne(float v) {
    unsigned u = __float_as_uint(v);
    return (unsigned short)((u + 0x7FFFu + ((u >> 16) & 1u)) >> 16);
}
// hi/lo split: v ~= hi + lo with ~17 bits of mantissa kept (bf16x3 scheme)
__device__ __forceinline__ void bf16split(float v, unsigned short& h, unsigned short& l) {
    h = bf16rne(v);
    float fh = __uint_as_float((unsigned)h << 16);
    l = bf16rne(v - fh);
}

__device__ __forceinline__ float sq3(float dx, float dy, float dz) {
    // match numpy: ((dx*dx + dy*dy) + dz*dz), no fma contraction
    return __fadd_rn(__fadd_rn(__fmul_rn(dx, dx), __fmul_rn(dy, dy)), __fmul_rn(dz, dz));
}

// One DPP max step on a packed u64 (non-negative): o = dpp(P); P = max(P,o).
// bound_ctrl=1 -> invalid lanes read 0; 0 is identity for our u64 max.
template<int CTRL, int RMASK>
__device__ __forceinline__ unsigned long long dpp_max_step(unsigned long long P) {
    int lo = __builtin_amdgcn_update_dpp(0, (int)(unsigned)P,        CTRL, RMASK, 0xf, true);
    int hi = __builtin_amdgcn_update_dpp(0, (int)(unsigned)(P >> 32), CTRL, RMASK, 0xf, true);
    unsigned long long o = ((unsigned long long)(unsigned)hi << 32) | (unsigned)lo;
    return (o > P) ? o : P;
}

// Full-wave u64 max via DPP (VALU-latency, no LDS shuffles). Result valid in lane 63.
__device__ __forceinline__ unsigned long long dpp_wave_max_u64(unsigned long long P) {
    P = dpp_max_step<0x111, 0xf>(P);   // row_shr:1
    P = dpp_max_step<0x112, 0xf>(P);   // row_shr:2
    P = dpp_max_step<0x114, 0xf>(P);   // row_shr:4
    P = dpp_max_step<0x118, 0xf>(P);   // row_shr:8
    P = dpp_max_step<0x142, 0xa>(P);   // row_bcast15
    P = dpp_max_step<0x143, 0xc>(P);   // row_bcast31 -> lane 63 has wave max
    return P;
}

__device__ __forceinline__ unsigned long long u64max(unsigned long long a, unsigned long long b) {
    return (a > b) ? a : b;
}

// ---------------- FPS (one block per batch, sequential argmax) ----------------
// r12 body — the EMPIRICAL OPTIMUM at ~306us. Do not change.
template<int NPTS, int NPOINT, int TPB>
__global__ __launch_bounds__(TPB) void fps_kernel(const float* __restrict__ xyz,
                                                  float* __restrict__ newxyz,
                                                  float* __restrict__ out_t,
                                                  int ts) {
    constexpr int PPT = NPTS / TPB;
    constexpr int NW  = TPB / 64;
    static_assert(NPOINT <= TPB, "far-history latch needs NPOINT <= TPB");
    __shared__ float sx[NPTS], sy[NPTS], sz[NPTS];
    __shared__ __align__(16) unsigned long long slot[2][NW];
    const int b = blockIdx.x;
    const int tid = threadIdx.x;
    const float* base = xyz + (size_t)b * NPTS * 3;
    for (int i = tid; i < NPTS; i += TPB) {
        sx[i] = base[i * 3 + 0];
        sy[i] = base[i * 3 + 1];
        sz[i] = base[i * 3 + 2];
    }
    __syncthreads();
    float px[PPT], py[PPT], pz[PPT], dist[PPT];
#pragma unroll
    for (int k = 0; k < PPT; k++) {
        int p = tid + k * TPB;
        px[k] = sx[p]; py[k] = sy[p]; pz[k] = sz[p];
        dist[k] = 1e10f;
    }
    int far = 0;
    int myfar = 0;
    const int lane = tid & 63, wid = tid >> 6;
    for (int it = 0; it < NPOINT; it++) {
        if (tid == it) myfar = far;          // latch entering-far for the final write
        float fx = sx[far], fy = sy[far], fz = sz[far];
        float bv = -1.0f; int bi = 0;
#pragma unroll
        for (int k = 0; k < PPT; k++) {
            float d = sq3(px[k] - fx, py[k] - fy, pz[k] - fz);
            float nd = fminf(dist[k], d);
            dist[k] = nd;
            if (nd > bv) { bv = nd; bi = tid + k * TPB; }   // strict > keeps smallest k
        }
        unsigned long long P = ((unsigned long long)__float_as_uint(bv) << 32)
                             | (unsigned long long)(~(unsigned)bi & 0xFFFFFFFFull);
        P = dpp_wave_max_u64(P);
        int bufi = it & 1;
        if (lane == 63) slot[bufi][wid] = P;
        __syncthreads();
        // log-tree: all slot loads issued upfront, then pairwise max
        unsigned long long v[NW];
#pragma unroll
        for (int w = 0; w < NW; w++) v[w] = slot[bufi][w];
#pragma unroll
        for (int st = NW / 2; st >= 1; st >>= 1)
#pragma unroll
            for (int w = 0; w < st; w++) v[w] = u64max(v[w], v[w + st]);
        far = (int)(~(unsigned)(v[0] & 0xFFFFFFFFull));
    }
    if (tid < NPOINT) {
        float fx = sx[myfar], fy = sy[myfar], fz = sz[myfar];
        newxyz[((size_t)b * NPOINT + tid) * 3 + 0] = fx;
        newxyz[((size_t)b * NPOINT + tid) * 3 + 1] = fy;
        newxyz[((size_t)b * NPOINT + tid) * 3 + 2] = fz;
        if (out_t) {
            out_t[0 * ts + b * NPOINT + tid] = fx;
            out_t[1 * ts + b * NPOINT + tid] = fy;
            out_t[2 * ts + b * NPOINT + tid] = fz;
        }
    }
}

// ---------------- ball query body: one wave per center, ballot rounds ----------------
template<int NS>
__device__ __forceinline__ void bq_body(const float* __restrict__ pts, int n,
                                        const float* __restrict__ centers, int S,
                                        float r2, int* __restrict__ outidx,
                                        int wave, int lane) {
    int b = wave / S, s = wave % S;
    const float* c = centers + ((size_t)b * S + s) * 3;
    float cx = c[0], cy = c[1], cz = c[2];
    const float* pb = pts + (size_t)b * n * 3;
    int* out = outidx + ((size_t)b * S + s) * NS;
    int total = 0, first = -1;
    int rounds = n >> 6;
    for (int r = 0; r < rounds; r++) {
        int p = (r << 6) + lane;
        float dx = pb[p * 3 + 0] - cx, dy = pb[p * 3 + 1] - cy, dz = pb[p * 3 + 2] - cz;
        float d = sq3(dx, dy, dz);
        bool pred = (d <= r2);
        unsigned long long mask = __ballot(pred);
        if (first < 0 && mask) first = (r << 6) + (__ffsll(mask) - 1);
        if (pred) {
            int rank = total + __popcll(mask & ((1ull << lane) - 1ull));
            if (rank < NS) out[rank] = p;
        }
        total += __popcll(mask);
        if (total >= NS) break;
    }
    for (int j = total + lane; j < NS; j += 64) out[j] = first;
}

// generic weight -> bf16 hi/lo B-fragment conversion (one uint4 per thread)
__device__ __forceinline__ void wconv_one(const float* __restrict__ W, float* __restrict__ OF,
                                          int NT, int KT, int N, int t) {
    int L = t & 63;
    int rest = t >> 6;                       // (hl*KT + kt)*NT + nt
    int nt = rest & (NT - 1);
    int hk = rest / NT;
    int kt = hk % KT, hl = hk / KT;
    int k0 = kt * 32 + (L >> 4) * 8;
    int n  = nt * 16 + (L & 15);
    unsigned o[4];
#pragma unroll
    for (int e = 0; e < 4; e++) {
        float va = W[(size_t)(k0 + 2 * e + 0) * N + n];
        float vb = W[(size_t)(k0 + 2 * e + 1) * N + n];
        unsigned short ha, la, hb, lb;
        bf16split(va, ha, la);
        bf16split(vb, hb, lb);
        o[e] = hl ? ((unsigned)la | ((unsigned)lb << 16))
                  : ((unsigned)ha | ((unsigned)hb << 16));
    }
    ((uint4*)OF)[t] = make_uint4(o[0], o[1], o[2], o[3]);
}

// ---------------- fused: fps2 single-wave (blocks 0..15) + ballquery1 (16..1039)
// ---------------- + weight MFMA-fragment conversion (blocks 1040..1077) ----------------
__global__ __launch_bounds__(512) void bq1_fps2_kernel(const float* __restrict__ points,
                                                       const float* __restrict__ l1x,
                                                       float* __restrict__ l2x,
                                                       float* __restrict__ x3t,
                                                       int* __restrict__ idx1,
                                                       float r2a,
                                                       const float* __restrict__ w21,
                                                       const float* __restrict__ w22,
                                                       const float* __restrict__ w11s,
                                                       const float* __restrict__ w12s,
                                                       const float* __restrict__ w20s,
                                                       float* __restrict__ w21f,
                                                       float* __restrict__ w22f,
                                                       float* __restrict__ w11f,
                                                       float* __restrict__ w12f,
                                                       float* __restrict__ w20f) {
    __shared__ float sx[512], sy[512], sz[512];
    const int tid = threadIdx.x;
    const int lane = tid & 63, wid = tid >> 6;
    if (blockIdx.x < 16) {
        if (wid != 0) return;    // single-wave fps2; no barriers in this path
        const int b = blockIdx.x;
        const float* base = l1x + (size_t)b * 512 * 3;
        for (int i = lane; i < 512; i += 64) {
            sx[i] = base[i * 3 + 0];
            sy[i] = base[i * 3 + 1];
            sz[i] = base[i * 3 + 2];
        }
        float px[8], py[8], pz[8], dist[8];
#pragma unroll
        for (int k = 0; k < 8; k++) {
            int p = lane + k * 64;
            px[k] = sx[p]; py[k] = sy[p]; pz[k] = sz[p];
            dist[k] = 1e10f;
        }
        int far = 0, myfar0 = 0, myfar1 = 0;
        for (int it = 0; it < 128; it++) {
            if (lane == it) myfar0 = far;
            if (lane == it - 64) myfar1 = far;
            float fx = sx[far], fy = sy[far], fz = sz[far];
            float bv = -1.0f; int bi = 0;
#pragma unroll
            for (int k = 0; k < 8; k++) {
                float d = sq3(px[k] - fx, py[k] - fy, pz[k] - fz);
                float nd = fminf(dist[k], d);
                dist[k] = nd;
                if (nd > bv) { bv = nd; bi = lane + k * 64; }
            }
            unsigned long long P = ((unsigned long long)__float_as_uint(bv) << 32)
                                 | (unsigned long long)(~(unsigned)bi & 0xFFFFFFFFull);
            P = dpp_wave_max_u64(P);
            unsigned lo = (unsigned)__builtin_amdgcn_readlane((int)(unsigned)P, 63);
            far = (int)(~lo);          // idx was stored as ~idx in low 32
        }
        {
            int s0 = lane, s1 = lane + 64;
            float a = sx[myfar0], c1 = sy[myfar0], c2 = sz[myfar0];
            l2x[((size_t)b * 128 + s0) * 3 + 0] = a;
            l2x[((size_t)b * 128 + s0) * 3 + 1] = c1;
            l2x[((size_t)b * 128 + s0) * 3 + 2] = c2;
            x3t[0 * 2048 + b * 128 + s0] = a;
            x3t[1 * 2048 + b * 128 + s0] = c1;
            x3t[2 * 2048 + b * 128 + s0] = c2;
            float d = sx[myfar1], e = sy[myfar1], f = sz[myfar1];
            l2x[((size_t)b * 128 + s1) * 3 + 0] = d;
            l2x[((size_t)b * 128 + s1) * 3 + 1] = e;
            l2x[((size_t)b * 128 + s1) * 3 + 2] = f;
            x3t[0 * 2048 + b * 128 + s1] = d;
            x3t[1 * 2048 + b * 128 + s1] = e;
            x3t[2 * 2048 + b * 128 + s1] = f;
        }
    } else if (blockIdx.x < 1040) {
        int wave = (blockIdx.x - 16) * 8 + wid;   // 1024 blocks x 8 waves = 8192
        bq_body<32>(points, 4096, l1x, 512, r2a, idx1, wave, lane);
    } else {
        // weight -> bf16 hi/lo MFMA-fragment conversion. 38 blocks x 512 thr = 19456
        int gt = (blockIdx.x - 1040) * 512 + tid;
        if (gt < 4096)       wconv_one(w21,        w21f, 8,  4, 128, gt);
        else if (gt < 12288) wconv_one(w22,        w22f, 16, 4, 256, gt - 4096);
        else if (gt < 13312) wconv_one(w11s,       w11f, 4,  2, 64,  gt - 12288);
        else if (gt < 15360) wconv_one(w12s,       w12f, 8,  2, 128, gt - 13312);
        else                 wconv_one(w20s + 384, w20f, 8,  4, 128, gt - 15360);  // w20 rows 3..130
    }
}

// ---------------- fused: ballquery2 (blocks 0..511, 4 waves each) ----------------
// ---------------- + SA1 MFMA (blocks 512..1535, 4 tasks/block) ----------------
// Same per-wave task bodies as the r5 6144x64 version, re-mapped onto 256-thread
// blocks (4 tasks each) to cut block count 6144 -> 1536 (block-dispatch overhead
// experiment). Per-task LDS slice 18 KB; 73.7 KB/block; (256,2) -> 8 waves/CU (same
// occupancy as before). Barriers couple 4 identical-control-flow tasks (safe).
__global__ __launch_bounds__(256, 2) void sa1_bq2_kernel(const float* __restrict__ xyz, const float* __restrict__ l1x,
                                                 const int* __restrict__ idx1,
                                                 const float* __restrict__ l2x, int* __restrict__ idx2, float r2b,
                                                 const float* __restrict__ W1, const float* __restrict__ B1,
                                                 const float* __restrict__ W2f, const float* __restrict__ B2,
                                                 const float* __restrict__ W3f, const float* __restrict__ B3,
                                                 float* __restrict__ l1f) {
    __shared__ short hshA[4][64 * 72];   // bf16 hi, [task][row*72+ch]
    __shared__ short hslA[4][64 * 72];   // bf16 lo
    int tid = threadIdx.x;
    int lane = tid & 63, wid = tid >> 6;   // 0..3
    if (blockIdx.x < 512) {
        int wave = blockIdx.x * 4 + wid;   // 0..2047
        bq_body<64>(l1x, 512, l2x, 128, r2b, idx2, wave, lane);
        return;
    }
    short* hsh = hshA[wid];
    short* hsl = hslA[wid];
    int t = (blockIdx.x - 512) * 4 + wid;        // 0..4095 (old blk)
    int b = t >> 8;
    int ct = lane >> 5, nn = lane & 31;
    int s = ((t & 255) << 1) | ct;
    int center = b * 512 + s;
    int c0 = b * 512 + ((t & 255) << 1);         // pooled-output centers
    int ii = idx1[center * 32 + nn];
    float px = xyz[((size_t)b * NN + ii) * 3 + 0] - l1x[(size_t)center * 3 + 0];
    float py = xyz[((size_t)b * NN + ii) * 3 + 1] - l1x[(size_t)center * 3 + 1];
    float pz = xyz[((size_t)b * NN + ii) * 3 + 2] - l1x[(size_t)center * 3 + 2];
    // layer1: 3->64, relu, split -> LDS row-major (row = lane)
#pragma unroll
    for (int c2 = 0; c2 < 32; c2++) {
        int ca = 2 * c2, cb = 2 * c2 + 1;
        float v0 = fmaxf(B1[ca] + px * W1[ca] + py * W1[64 + ca] + pz * W1[128 + ca], 0.0f);
        float v1 = fmaxf(B1[cb] + px * W1[cb] + py * W1[64 + cb] + pz * W1[128 + cb], 0.0f);
        unsigned short h0, l0, h1, l1;
        bf16split(v0, h0, l0);
        bf16split(v1, h1, l1);
        int base = lane * 72 + ca;
        *(unsigned*)(&hsh[base]) = (unsigned)h0 | ((unsigned)h1 << 16);
        *(unsigned*)(&hsl[base]) = (unsigned)l0 | ((unsigned)l1 << 16);
    }
    __syncthreads();
    // ---- layer2: [64x64] = relu([64x64] x w11 + b11), MFMA bf16x3 ----
    {
        fx4 acc[4][4];
#pragma unroll
        for (int mt = 0; mt < 4; mt++)
#pragma unroll
            for (int nt = 0; nt < 4; nt++) {
                float bn = B2[nt * 16 + (lane & 15)];
                acc[mt][nt] = (fx4){bn, bn, bn, bn};
            }
        const bfrag8* w2v = (const bfrag8*)W2f;
#pragma unroll
        for (int kt = 0; kt < 2; kt++) {
            bfrag8 ah[4], al[4];
#pragma unroll
            for (int mt = 0; mt < 4; mt++) {
                int idx = (mt * 16 + (lane & 15)) * 72 + kt * 32 + (lane >> 4) * 8;
                ah[mt] = *(const bfrag8*)(&hsh[idx]);
                al[mt] = *(const bfrag8*)(&hsl[idx]);
            }
#pragma unroll
            for (int nt = 0; nt < 4; nt++) {
                bfrag8 bh = w2v[(size_t)((0 + kt) * 4 + nt) * 64 + lane];
                bfrag8 bl = w2v[(size_t)((2 + kt) * 4 + nt) * 64 + lane];
#pragma unroll
                for (int mt = 0; mt < 4; mt++) {
                    acc[mt][nt] = mfma16(ah[mt], bh, acc[mt][nt]);
                    acc[mt][nt] = mfma16(ah[mt], bl, acc[mt][nt]);
                    acc[mt][nt] = mfma16(al[mt], bh, acc[mt][nt]);
                }
            }
        }
        __syncthreads();
        // relu + split back to LDS (C/D map: m = mt*16 + (lane>>4)*4 + r, n = nt*16 + (lane&15))
#pragma unroll
        for (int mt = 0; mt < 4; mt++)
#pragma unroll
            for (int nt = 0; nt < 4; nt++)
#pragma unroll
                for (int r = 0; r < 4; r++) {
                    float v = fmaxf(acc[mt][nt][r], 0.0f);
                    int m = mt * 16 + (lane >> 4) * 4 + r;
                    int n = nt * 16 + (lane & 15);
                    unsigned short hb, lb;
                    bf16split(v, hb, lb);
                    hsh[m * 72 + n] = (short)hb;
                    hsl[m * 72 + n] = (short)lb;
                }
        __syncthreads();
    }
    // ---- layer3: [64x128] = relu([64x64] x w12 + b12), MFMA bf16x3, max-pool per center ----
    const bfrag8* w3v = (const bfrag8*)W3f;
#pragma unroll 1
    for (int pass = 0; pass < 2; pass++) {
        int nbase = pass * 4;
        fx4 acc[4][4];
#pragma unroll
        for (int mt = 0; mt < 4; mt++)
#pragma unroll
            for (int nt = 0; nt < 4; nt++) {
                float bn = B3[(nbase + nt) * 16 + (lane & 15)];
                acc[mt][nt] = (fx4){bn, bn, bn, bn};
            }
#pragma unroll
        for (int kt = 0; kt < 2; kt++) {
            bfrag8 ah[4], al[4];
#pragma unroll
            for (int mt = 0; mt < 4; mt++) {
                int idx = (mt * 16 + (lane & 15)) * 72 + kt * 32 + (lane >> 4) * 8;
                ah[mt] = *(const bfrag8*)(&hsh[idx]);
                al[mt] = *(const bfrag8*)(&hsl[idx]);
            }
#pragma unroll
            for (int nt = 0; nt < 4; nt++) {
                bfrag8 bh = w3v[(size_t)((0 + kt) * 8 + nbase + nt) * 64 + lane];
                bfrag8 bl = w3v[(size_t)((2 + kt) * 8 + nbase + nt) * 64 + lane];
#pragma unroll
                for (int mt = 0; mt < 4; mt++) {
                    acc[mt][nt] = mfma16(ah[mt], bh, acc[mt][nt]);
                    acc[mt][nt] = mfma16(ah[mt], bl, acc[mt][nt]);
                    acc[mt][nt] = mfma16(al[mt], bh, acc[mt][nt]);
                }
            }
        }
        // pool: rows 0..31 -> center c0, rows 32..63 -> c0+1. relu(max) = max(max,0).
#pragma unroll
        for (int nt = 0; nt < 4; nt++) {
            float mv0 = 0.0f, mv1 = 0.0f;
#pragma unroll
            for (int r = 0; r < 4; r++) {
                mv0 = fmaxf(mv0, fmaxf(acc[0][nt][r], acc[1][nt][r]));
                mv1 = fmaxf(mv1, fmaxf(acc[2][nt][r], acc[3][nt][r]));
            }
            mv0 = fmaxf(mv0, __shfl_xor(mv0, 16));
            mv0 = fmaxf(mv0, __shfl_xor(mv0, 32));
            mv1 = fmaxf(mv1, __shfl_xor(mv1, 16));
            mv1 = fmaxf(mv1, __shfl_xor(mv1, 32));
            int n = (nbase + nt) * 16 + (lane & 15);
            if (lane < 16)      l1f[(size_t)c0 * 128 + n] = mv0;
            else if (lane < 32) l1f[(size_t)(c0 + 1) * 128 + n] = mv1;
        }
    }
}

// ---------------- SA2 MLP: 131->128->128->256, max over 64 nbrs — ALL layers MFMA ----------------
__global__ __launch_bounds__(256, 4) void sa2_kernel(const float* __restrict__ l1x, const float* __restrict__ l2x,
                                                  const float* __restrict__ l1f, const int* __restrict__ idx2,
                                                  const float* __restrict__ W1, const float* __restrict__ B1,
                                                  const float* __restrict__ w20f,
                                                  const float* __restrict__ w21f, const float* __restrict__ B2,
                                                  const float* __restrict__ w22f, const float* __restrict__ B3,
                                                  float* __restrict__ x3t) {
    __shared__ short hsh[64 * 136];   // bf16 hi, [nbr][ch], stride 136 shorts
    __shared__ short hsl[64 * 136];   // bf16 lo
    __shared__ float sxyz[64 * 4];    // centered xyz per row (stride 4)
    int tid = threadIdx.x;
    int w = __builtin_amdgcn_readfirstlane(tid >> 6);   // 0..3, wave-uniform -> SGPR
    int lane = tid & 63;
    int b = blockIdx.x >> 7, s = blockIdx.x & 127;
    int center = b * 128 + s;
    int ii = idx2[center * 64 + lane];
    float cx = l2x[(size_t)center * 3 + 0], cy = l2x[(size_t)center * 3 + 1], cz = l2x[(size_t)center * 3 + 2];
    const float* pr = l1x + ((size_t)b * 512 + ii) * 3;
    float px = pr[0] - cx, py = pr[1] - cy, pz = pr[2] - cz;
    if (w == 0) {
        sxyz[lane * 4 + 0] = px;
        sxyz[lane * 4 + 1] = py;
        sxyz[lane * 4 + 2] = pz;
    }
    // stage gathered features: wave w handles ch 32w..32w+31
    {
        const float4* frow = (const float4*)(l1f + ((size_t)b * 512 + ii) * 128);
#pragma unroll
        for (int j = 0; j < 8; j++) {
            float4 f = frow[w * 8 + j];
            unsigned short h0, l0, h1, l1, h2, l2, h3, l3;
            bf16split(f.x, h0, l0);
            bf16split(f.y, h1, l1);
            bf16split(f.z, h2, l2);
            bf16split(f.w, h3, l3);
            int cb = lane * 136 + w * 32 + 4 * j;
            *(unsigned*)(&hsh[cb + 0]) = (unsigned)h0 | ((unsigned)h1 << 16);
            *(unsigned*)(&hsh[cb + 2]) = (unsigned)h2 | ((unsigned)h3 << 16);
            *(unsigned*)(&hsl[cb + 0]) = (unsigned)l0 | ((unsigned)l1 << 16);
            *(unsigned*)(&hsl[cb + 2]) = (unsigned)l2 | ((unsigned)l3 << 16);
        }
    }
    __syncthreads();
    // ---- layer1: [64x128] = relu(feat[64x128] x w20[3:] + xyz x w20[0:3] + b20), MFMA bf16x3 ----
    {
        fx4 acc[4][2];
        float w0n[2], w1n[2], w2n[2];
#pragma unroll
        for (int nt = 0; nt < 2; nt++) {
            int n = (2 * w + nt) * 16 + (lane & 15);
            float bn = B1[n];
            acc[0][nt] = (fx4){bn, bn, bn, bn};
            acc[1][nt] = acc[0][nt]; acc[2][nt] = acc[0][nt]; acc[3][nt] = acc[0][nt];
            w0n[nt] = W1[n]; w1n[nt] = W1[128 + n]; w2n[nt] = W1[256 + n];
        }
        // xyz rank-3 correction into C fragments
#pragma unroll
        for (int mt = 0; mt < 4; mt++)
#pragma unroll
            for (int r = 0; r < 4; r++) {
                int m = mt * 16 + (lane >> 4) * 4 + r;
                float mx = sxyz[m * 4 + 0], my = sxyz[m * 4 + 1], mz = sxyz[m * 4 + 2];
#pragma unroll
                for (int nt = 0; nt < 2; nt++)
                    acc[mt][nt][r] += mx * w0n[nt] + my * w1n[nt] + mz * w2n[nt];
            }
#pragma unroll
        for (int kt = 0; kt < 4; kt++) {
            bfrag8 ah[4], al[4];
#pragma unroll
            for (int mt = 0; mt < 4; mt++) {
                int idx = (mt * 16 + (lane & 15)) * 136 + kt * 32 + (lane >> 4) * 8;
                ah[mt] = *(const bfrag8*)(&hsh[idx]);
                al[mt] = *(const bfrag8*)(&hsl[idx]);
            }
#pragma unroll
            for (int nt = 0; nt < 2; nt++) {
                int ng = 2 * w + nt;
                bfrag8 bh = ((const bfrag8*)w20f)[(size_t)((0 + kt) * 8 + ng) * 64 + lane];
                bfrag8 bl = ((const bfrag8*)w20f)[(size_t)((4 + kt) * 8 + ng) * 64 + lane];
#pragma unroll
                for (int mt = 0; mt < 4; mt++) {
                    acc[mt][nt] = mfma16(ah[mt], bh, acc[mt][nt]);
                    acc[mt][nt] = mfma16(ah[mt], bl, acc[mt][nt]);
                    acc[mt][nt] = mfma16(al[mt], bh, acc[mt][nt]);
                }
            }
        }
        __syncthreads();   // all waves done reading feat -> safe to overwrite
#pragma unroll
        for (int mt = 0; mt < 4; mt++)
#pragma unroll
            for (int nt = 0; nt < 2; nt++)
#pragma unroll
                for (int r = 0; r < 4; r++) {
                    float v = fmaxf(acc[mt][nt][r], 0.0f);
                    int m = mt * 16 + (lane >> 4) * 4 + r;
                    int n = (2 * w + nt) * 16 + (lane & 15);
                    unsigned short hb, lb;
                    bf16split(v, hb, lb);
                    hsh[m * 136 + n] = (short)hb;
                    hsl[m * 136 + n] = (short)lb;
                }
        __syncthreads();
    }
    // ---- layer2: [64x128] = relu([64x128] x w21 + b21), MFMA bf16x3 ----
    {
        fx4 acc[4][2];
#pragma unroll
        for (int mt = 0; mt < 4; mt++)
#pragma unroll
            for (int nt = 0; nt < 2; nt++) {
                float bn = B2[(2 * w + nt) * 16 + (lane & 15)];
                acc[mt][nt] = (fx4){bn, bn, bn, bn};
            }
#pragma unroll
        for (int kt = 0; kt < 4; kt++) {
            bfrag8 ah[4], al[4];
#pragma unroll
            for (int mt = 0; mt < 4; mt++) {
                int idx = (mt * 16 + (lane & 15)) * 136 + kt * 32 + (lane >> 4) * 8;
                ah[mt] = *(const bfrag8*)(&hsh[idx]);
                al[mt] = *(const bfrag8*)(&hsl[idx]);
            }
#pragma unroll
            for (int nt = 0; nt < 2; nt++) {
                int ng = 2 * w + nt;
                bfrag8 bh = ((const bfrag8*)w21f)[(size_t)((0 + kt) * 8 + ng) * 64 + lane];
                bfrag8 bl = ((const bfrag8*)w21f)[(size_t)((4 + kt) * 8 + ng) * 64 + lane];
#pragma unroll
                for (int mt = 0; mt < 4; mt++) {
                    acc[mt][nt] = mfma16(ah[mt], bh, acc[mt][nt]);
                    acc[mt][nt] = mfma16(ah[mt], bl, acc[mt][nt]);
                    acc[mt][nt] = mfma16(al[mt], bh, acc[mt][nt]);
                }
            }
        }
        __syncthreads();   // all waves done reading layer1 acts -> safe to overwrite
#pragma unroll
        for (int mt = 0; mt < 4; mt++)
#pragma unroll
            for (int nt = 0; nt < 2; nt++)
#pragma unroll
                for (int r = 0; r < 4; r++) {
                    float v = fmaxf(acc[mt][nt][r], 0.0f);
                    int m = mt * 16 + (lane >> 4) * 4 + r;
                    int n = (2 * w + nt) * 16 + (lane & 15);
                    unsigned short hb, lb;
                    bf16split(v, hb, lb);
                    hsh[m * 136 + n] = (short)hb;
                    hsl[m * 136 + n] = (short)lb;
                }
        __syncthreads();
    }
    // ---- layer3: [64x256] = relu([64x128] x w22 + b22), MFMA bf16x3, then max over 64 nbrs ----
#pragma unroll 1
    for (int pass = 0; pass < 2; pass++) {
        int nb = w * 4 + pass * 2;            // global n-tile base (of 16)
        fx4 acc[4][2];
#pragma unroll
        for (int mt = 0; mt < 4; mt++)
#pragma unroll
            for (int nt = 0; nt < 2; nt++) {
                float bn = B3[(nb + nt) * 16 + (lane & 15)];
                acc[mt][nt] = (fx4){bn, bn, bn, bn};
            }
#pragma unroll
        for (int kt = 0; kt < 4; kt++) {
            bfrag8 ah[4], al[4];
#pragma unroll
            for (int mt = 0; mt < 4; mt++) {
                int idx = (mt * 16 + (lane & 15)) * 136 + kt * 32 + (lane >> 4) * 8;
                ah[mt] = *(const bfrag8*)(&hsh[idx]);
                al[mt] = *(const bfrag8*)(&hsl[idx]);
            }
#pragma unroll
            for (int nt = 0; nt < 2; nt++) {
                bfrag8 bh = ((const bfrag8*)w22f)[(size_t)((0 + kt) * 16 + (nb + nt)) * 64 + lane];
                bfrag8 bl = ((const bfrag8*)w22f)[(size_t)((4 + kt) * 16 + (nb + nt)) * 64 + lane];
#pragma unroll
                for (int mt = 0; mt < 4; mt++) {
                    acc[mt][nt] = mfma16(ah[mt], bh, acc[mt][nt]);
                    acc[mt][nt] = mfma16(ah[mt], bl, acc[mt][nt]);
                    acc[mt][nt] = mfma16(al[mt], bh, acc[mt][nt]);
                }
            }
        }
#pragma unroll
        for (int nt = 0; nt < 2; nt++) {
            float mv = 0.0f;   // relu(max) == max(max, 0)
#pragma unroll
            for (int mt = 0; mt < 4; mt++)
#pragma unroll
                for (int r = 0; r < 4; r++)
                    mv = fmaxf(mv, acc[mt][nt][r]);
            mv = fmaxf(mv, __shfl_xor(mv, 16));
            mv = fmaxf(mv, __shfl_xor(mv, 32));
            if (lane < 16)
                x3t[(size_t)(3 + (nb + nt) * 16 + lane) * 2048 + center] = mv;
        }
    }
}

// ---------------- gemm1 body (pkfma, bf16 hi/lo out) ----------------
template<int K, int COUT, int CPT>
__device__ __forceinline__ void gemm1_body_bf16out(const float* __restrict__ in_t,
                                                   const float* __restrict__ W,
                                                   const float* __restrict__ bias,
                                                   unsigned short* __restrict__ oh,
                                                   unsigned short* __restrict__ ol,
                                                   int bid, int lane) {
    int rw = bid & 31, cg = bid >> 5;
    int row = rw * 64 + lane;
    int cbase = cg * CPT;
    v2f acc[CPT / 2];
    const v2f* bv = (const v2f*)(bias + cbase);
#pragma unroll
    for (int j = 0; j < CPT / 2; j++) acc[j] = bv[j];
    for (int k = 0; k < K; k++) {
        float xk = in_t[(size_t)k * 2048 + row];
        v2f xk2 = {xk, xk};
        const v2f* wr = (const v2f*)(W + (size_t)k * COUT + cbase);
#pragma unroll
        for (int j = 0; j < CPT / 2; j++) acc[j] = pkfma(xk2, wr[j], acc[j]);
    }
    unsigned ho[4], lo[4];
#pragma unroll
    for (int j = 0; j < CPT / 2; j++) {
        float va = fmaxf(acc[j].x, 0.0f);
        float vb = fmaxf(acc[j].y, 0.0f);
        unsigned short ha, la, hb, lb;
        bf16split(va, ha, la);
        bf16split(vb, hb, lb);
        ho[j] = (unsigned)ha | ((unsigned)hb << 16);
        lo[j] = (unsigned)la | ((unsigned)lb << 16);
    }
    size_t idx = ((size_t)row * COUT + cbase) >> 3;   // uint4 index
    ((uint4*)oh)[idx] = make_uint4(ho[0], ho[1], ho[2], ho[3]);
    ((uint4*)ol)[idx] = make_uint4(lo[0], lo[1], lo[2], lo[3]);
}

// gemm1 (vw 0..1023) + zero-init of g (vw 1024..1279) + w31/w32 frag conv (vw 1280..3839)
// 480 blocks x 512 thr (vw = bid*8 + wid) — same per-wave tasks as the 3840x64 version.
__global__ __launch_bounds__(512) void gemm1_zerog_kernel(const float* __restrict__ in_t,
                                                            const float* __restrict__ W,
                                                            const float* __restrict__ bias,
                                                            unsigned short* __restrict__ h1h,
                                                            unsigned short* __restrict__ h1l,
                                                            float* __restrict__ g,
                                                            const float* __restrict__ w31,
                                                            const float* __restrict__ w32,
                                                            float* __restrict__ w31f,
                                                            float* __restrict__ w32f) {
    int lane = threadIdx.x & 63;
    int vw = blockIdx.x * 8 + (threadIdx.x >> 6);   // 0..3839
    if (vw < 1024) {
        gemm1_body_bf16out<259, 256, 8>(in_t, W, bias, h1h, h1l, vw, lane);
    } else if (vw < 1280) {
        g[(vw - 1024) * 64 + lane] = 0.0f;
    } else {
        int gt = (vw - 1280) * 64 + lane;
        if (gt < 32768) wconv_one(w31, w31f, 32, 8,  512,  gt);
        else            wconv_one(w32, w32f, 64, 16, 1024, gt - 32768);
    }
}

// ---------------- MFMA GEMM body on bf16 hi/lo planes (A from global, no LDS) ----------------
template<int K, int NT_TOT, bool MAXOUT>
__device__ __forceinline__ void gemm_mfma_body(const unsigned short* __restrict__ Ah,
                                               const unsigned short* __restrict__ Al,
                                               const float* __restrict__ Wf,
                                               const float* __restrict__ bias,
                                               unsigned short* __restrict__ Oh,
                                               unsigned short* __restrict__ Ol,
                                               float* __restrict__ g,
                                               int bid, int lane) {
    constexpr int KT = K / 32;
    constexpr int NCOL = NT_TOT * 16;
    int mtile = bid & 31, bn = bid >> 5;
    int mbase = mtile * 64;
    int nb4 = bn * 4;                       // base nt16 group (4 per wave = 64 cols)
    const bfrag8* wv = (const bfrag8*)Wf;
    fx4 acc[4][4];
#pragma unroll
    for (int mt = 0; mt < 4; mt++)
#pragma unroll
        for (int j = 0; j < 4; j++) {
            float bnv = bias[(nb4 + j) * 16 + (lane & 15)];
            acc[mt][j] = (fx4){bnv, bnv, bnv, bnv};
        }
#pragma unroll 1
    for (int kt = 0; kt < KT; kt++) {
        bfrag8 ah[4], al[4];
#pragma unroll
        for (int mt = 0; mt < 4; mt++) {
            size_t off = (size_t)(mbase + mt * 16 + (lane & 15)) * K + kt * 32 + (lane >> 4) * 8;
            ah[mt] = *(const bfrag8*)(Ah + off);
            al[mt] = *(const bfrag8*)(Al + off);
        }
#pragma unroll
        for (int j = 0; j < 4; j++) {
            bfrag8 bh = wv[(size_t)((0 * KT + kt) * NT_TOT + nb4 + j) * 64 + lane];
            bfrag8 bl = wv[(size_t)((1 * KT + kt) * NT_TOT + nb4 + j) * 64 + lane];
#pragma unroll
            for (int mt = 0; mt < 4; mt++) {
                acc[mt][j] = mfma16(ah[mt], bh, acc[mt][j]);
                acc[mt][j] = mfma16(ah[mt], bl, acc[mt][j]);
                acc[mt][j] = mfma16(al[mt], bh, acc[mt][j]);
            }
        }
    }
    if (MAXOUT) {
        int b = mbase >> 7;                 // 64-row tile lies in one 128-row batch
#pragma unroll
        for (int j = 0; j < 4; j++) {
            float mv = 0.0f;                // relu(max) == max(max, 0)
#pragma unroll
            for (int mt = 0; mt < 4; mt++)
#pragma unroll
                for (int r = 0; r < 4; r++)
                    mv = fmaxf(mv, acc[mt][j][r]);
            mv = fmaxf(mv, __shfl_xor(mv, 16));
            mv = fmaxf(mv, __shfl_xor(mv, 32));
            if (lane < 16)
                atomicMax((int*)(g + (size_t)b * 1024 + (nb4 + j) * 16 + lane), __float_as_int(mv));
        }
    } else {
#pragma unroll
        for (int mt = 0; mt < 4; mt++)
#pragma unroll
            for (int j = 0; j < 4; j++)
#pragma unroll
                for (int r = 0; r < 4; r++) {
                    float v = fmaxf(acc[mt][j][r], 0.0f);
                    int m = mbase + mt * 16 + (lane >> 4) * 4 + r;
                    int n = (nb4 + j) * 16 + (lane & 15);
                    unsigned short hb, lb;
                    bf16split(v, hb, lb);
                    Oh[(size_t)m * NCOL + n] = hb;
                    Ol[(size_t)m * NCOL + n] = lb;
                }
    }
}

// 8 virtual waves per 512-thr block (block-count reduction; per-wave math unchanged)
template<int K, int NT_TOT, bool MAXOUT>
__global__ __launch_bounds__(512) void gemm_mfma8_kernel(const unsigned short* __restrict__ Ah,
                                                         const unsigned short* __restrict__ Al,
                                                         const float* __restrict__ Wf,
                                                         const float* __restrict__ bias,
                                                         unsigned short* __restrict__ Oh,
                                                         unsigned short* __restrict__ Ol,
                                                         float* __restrict__ g) {
    int lane = threadIdx.x & 63;
    int vw = blockIdx.x * 8 + (threadIdx.x >> 6);
    gemm_mfma_body<K, NT_TOT, MAXOUT>(Ah, Al, Wf, bias, Oh, Ol, g, vw, lane);
}

// ---------------- FC heads ----------------
__global__ __launch_bounds__(512) void head_kernel(const float* __restrict__ g,
                                                   const float* __restrict__ lw1, const float* __restrict__ lb1,
                                                   const float* __restrict__ lw2, const float* __restrict__ lb2,
                                                   const float* __restrict__ fw1, const float* __restrict__ fb1,
                                                   const float* __restrict__ fw2, const float* __restrict__ fb2,
                                                   const float* __restrict__ pm, const float* __restrict__ ps,
                                                   const float* __restrict__ rm, const float* __restrict__ rs,
                                                   float* __restrict__ out) {
    __shared__ float gl[1024], a1[256], f1[512];
    int b = blockIdx.x, t = threadIdx.x;
    for (int i = t; i < 1024; i += 512) gl[i] = g[b * 1024 + i];
    __syncthreads();
    {
        float acc = fb1[t];
        for (int k = 0; k < 1024; k++) acc += gl[k] * fw1[k * 512 + t];
        f1[t] = fmaxf(acc, 0.0f);
    }
    if (t < 256) {
        float acc = lb1[t];
        for (int k = 0; k < 1024; k++) acc += gl[k] * lw1[k * 256 + t];
        a1[t] = fmaxf(acc, 0.0f);
    }
    __syncthreads();
    if (t < 2) {
        float z = lb2[t];
        for (int k = 0; k < 256; k++) z += a1[k] * lw2[k * 2 + t];
        out[b * 20 + t] = 1.0f / (1.0f + expf(-z));
    } else if (t < 20) {
        int i = t - 2;
        float z = fb2[i];
        for (int k = 0; k < 512; k++) z += f1[k] * fw2[k * 18 + i];
        float sc, mn;
        if (i < 3)       { sc = ps[i];      mn = pm[i]; }
        else if (i < 9)  { sc = rs[i - 3];  mn = rm[i - 3]; }
        else if (i < 12) { sc = ps[i - 9];  mn = pm[i - 9]; }
        else             { sc = rs[i - 12]; mn = rm[i - 12]; }
        out[b * 20 + t] = z * sc + mn;
    }
}

static inline size_t align256(size_t x) { return (x + 255) & ~(size_t)255; }

extern "C" void kernel_launch(void* const* d_in, const int* in_sizes, int n_in,
                              void* d_out, int out_size, void* d_ws, size_t ws_size,
                              hipStream_t stream) {
    const float* points = (const float*)d_in[0];
    const float* w10 = (const float*)d_in[1];  const float* b10 = (const float*)d_in[2];
    const float* w11 = (const float*)d_in[3];  const float* b11 = (const float*)d_in[4];
    const float* w12 = (const float*)d_in[5];  const float* b12 = (const float*)d_in[6];
    const float* w20 = (const float*)d_in[7];  const float* b20 = (const float*)d_in[8];
    const float* w21 = (const float*)d_in[9];  const float* b21 = (const float*)d_in[10];
    const float* w22 = (const float*)d_in[11]; const float* b22 = (const float*)d_in[12];
    const float* w30 = (const float*)d_in[13]; const float* b30 = (const float*)d_in[14];
    const float* w31 = (const float*)d_in[15]; const float* b31 = (const float*)d_in[16];
    const float* w32 = (const float*)d_in[17]; const float* b32 = (const float*)d_in[18];
    const float* lw1 = (const float*)d_in[19]; const float* lb1 = (const float*)d_in[20];
    const float* lw2 = (const float*)d_in[21]; const float* lb2 = (const float*)d_in[22];
    const float* fw1 = (const float*)d_in[23]; const float* fb1 = (const float*)d_in[24];
    const float* fw2 = (const float*)d_in[25]; const float* fb2 = (const float*)d_in[26];
    const float* pm  = (const float*)d_in[27]; const float* ps  = (const float*)d_in[28];
    const float* rm  = (const float*)d_in[29]; const float* rs  = (const float*)d_in[30];
    float* out = (float*)d_out;

    char* p = (char*)d_ws;
    float* l1x  = (float*)p; p += align256((size_t)BB * 512 * 3 * 4);
    int*   idx1 = (int*)p;   p += align256((size_t)BB * 512 * 32 * 4);
    float* l1f  = (float*)p; p += align256((size_t)BB * 512 * 128 * 4);
    float* l2x  = (float*)p; p += align256((size_t)BB * 128 * 3 * 4);
    int*   idx2 = (int*)p;   p += align256((size_t)BB * 128 * 64 * 4);
    float* x3t  = (float*)p; p += align256((size_t)259 * 2048 * 4);
    float* h1t  = (float*)p; p += align256((size_t)256 * 2048 * 4);
    float* h2t  = (float*)p; p += align256((size_t)512 * 2048 * 4);
    float* g    = (float*)p; p += align256((size_t)BB * 1024 * 4);
    // SA weight fragments (304 KB) alias head of h1t: produced by bq1_fps2, consumed by
    // sa1_bq2/sa2; h1t's first overwrite (gemm1_zerog h1 planes) is stream-ordered after.
    float* w21f = h1t;                                   // 64 KB
    float* w22f = h1t + (size_t)16384;                   // 128 KB
    float* w11f = h1t + (size_t)49152;                   // 16 KB
    float* w12f = h1t + (size_t)53248;                   // 32 KB
    float* w20f = h1t + (size_t)61440;                   // 64 KB
    // h1/h2 as bf16 hi/lo planes in the SAME footprint as the old fp32 buffers.
    unsigned short* h1h = (unsigned short*)h1t;                       // 1 MB (2048x256)
    unsigned short* h1l = h1h + (size_t)2048 * 256;                   // 1 MB
    unsigned short* h2h = (unsigned short*)h2t;                       // 2 MB (2048x512)
    unsigned short* h2l = h2h + (size_t)2048 * 512;                   // 2 MB
    // gemm2/3 weight fragments (2.5 MB) alias l1f (4 MB): converted in gemm1_zerog,
    // which runs after sa2 (last l1f reader). Consumed by gemm2/gemm3.
    float* w31f = l1f;                                   // 512 KB
    float* w32f = l1f + (size_t)131072;                  // 2 MB

    const float R2A = (float)(0.2 * 0.2);
    const float R2B = (float)(0.4 * 0.4);

    fps_kernel<4096, 512, 512><<<BB, 512, 0, stream>>>(points, l1x, (float*)nullptr, 0);
    bq1_fps2_kernel<<<1078, 512, 0, stream>>>(points, l1x, l2x, x3t, idx1, R2A,
                                              w21, w22, w11, w12, w20,
                                              w21f, w22f, w11f, w12f, w20f);
    sa1_bq2_kernel<<<1536, 256, 0, stream>>>(points, l1x, idx1, l2x, idx2, R2B,
                                             w10, b10, w11f, b11, w12f, b12, l1f);
    sa2_kernel<<<2048, 256, 0, stream>>>(l1x, l2x, l1f, idx2, w20, b20,
                                         w20f, w21f, b21, w22f, b22, x3t);
    gemm1_zerog_kernel<<<480, 512, 0, stream>>>(x3t, w30, b30, h1h, h1l, g, w31, w32, w31f, w32f);
    gemm_mfma8_kernel<256, 32, false><<<32, 512, 0, stream>>>(h1h, h1l, w31f, b31, h2h, h2l, (float*)nullptr);
    gemm_mfma8_kernel<512, 64, true><<<64, 512, 0, stream>>>(h2h, h2l, w32f, b32,
                                                             (unsigned short*)nullptr, (unsigned short*)nullptr, g);
    head_kernel<<<BB, 512, 0, stream>>>(g, lw1, lb1, lw2, lb2, fw1, fb1, fw2, fb2, pm, ps, rm, rs, out);
}

// Round 10
// 761.401 us; speedup vs baseline: 1.0407x; 1.0407x over previous
//
#include <hip/hip_runtime.h>
#include <math.h>

#define BB 16
#define NN 4096

typedef float v2f __attribute__((ext_vector_type(2)));
typedef short bfrag8 __attribute__((ext_vector_type(8)));   // 8 bf16 (4 VGPR) MFMA A/B frag
typedef float fx4 __attribute__((ext_vector_type(4)));      // MFMA C/D frag

__device__ __forceinline__ v2f pkfma(v2f a, v2f b, v2f c) {
    return __builtin_elementwise_fma(a, b, c);   // -> v_pk_fma_f32 on gfx950
}

__device__ __forceinline__ fx4 mfma16(bfrag8 a, bfrag8 b, fx4 c) {
    return __builtin_amdgcn_mfma_f32_16x16x32_bf16(a, b, c, 0, 0, 0);
}

// round-to-nearest-even fp32 -> bf16 bits (no NaN handling needed here)
__device__ __forceinline__ unsigned short bf16rne(float v) {
    unsigned u = __float_as_uint(v);
    return (unsigned short)((u + 0x7FFFu + ((u >> 16) & 1u)) >> 16);
}
// hi/lo split: v ~= hi + lo with ~17 bits of mantissa kept (bf16x3 scheme)
__device__ __forceinline__ void bf16split(float v, unsigned short& h, unsigned short& l) {
    h = bf16rne(v);
    float fh = __uint_as_float((unsigned)h << 16);
    l = bf16rne(v - fh);
}

__device__ __forceinline__ float sq3(float dx, float dy, float dz) {
    // match numpy: ((dx*dx + dy*dy) + dz*dz), no fma contraction
    return __fadd_rn(__fadd_rn(__fmul_rn(dx, dx), __fmul_rn(dy, dy)), __fmul_rn(dz, dz));
}

// One DPP max step on a packed u64 (non-negative): o = dpp(P); P = max(P,o).
// bound_ctrl=1 -> invalid lanes read 0; 0 is identity for our u64 max.
template<int CTRL, int RMASK>
__device__ __forceinline__ unsigned long long dpp_max_step(unsigned long long P) {
    int lo = __builtin_amdgcn_update_dpp(0, (int)(unsigned)P,        CTRL, RMASK, 0xf, true);
    int hi = __builtin_amdgcn_update_dpp(0, (int)(unsigned)(P >> 32), CTRL, RMASK, 0xf, true);
    unsigned long long o = ((unsigned long long)(unsigned)hi << 32) | (unsigned)lo;
    return (o > P) ? o : P;
}

// Full-wave u64 max via DPP (VALU-latency, no LDS shuffles). Result valid in lane 63.
__device__ __forceinline__ unsigned long long dpp_wave_max_u64(unsigned long long P) {
    P = dpp_max_step<0x111, 0xf>(P);   // row_shr:1
    P = dpp_max_step<0x112, 0xf>(P);   // row_shr:2
    P = dpp_max_step<0x114, 0xf>(P);   // row_shr:4
    P = dpp_max_step<0x118, 0xf>(P);   // row_shr:8
    P = dpp_max_step<0x142, 0xa>(P);   // row_bcast15
    P = dpp_max_step<0x143, 0xc>(P);   // row_bcast31 -> lane 63 has wave max
    return P;
}

__device__ __forceinline__ unsigned long long u64max(unsigned long long a, unsigned long long b) {
    return (a > b) ? a : b;
}

// ---------------- FPS (one block per batch, sequential argmax) ----------------
// r12 body — the EMPIRICAL OPTIMUM at ~306us. Do not change.
template<int NPTS, int NPOINT, int TPB>
__global__ __launch_bounds__(TPB) void fps_kernel(const float* __restrict__ xyz,
                                                  float* __restrict__ newxyz,
                                                  float* __restrict__ out_t,
                                                  int ts) {
    constexpr int PPT = NPTS / TPB;
    constexpr int NW  = TPB / 64;
    static_assert(NPOINT <= TPB, "far-history latch needs NPOINT <= TPB");
    __shared__ float sx[NPTS], sy[NPTS], sz[NPTS];
    __shared__ __align__(16) unsigned long long slot[2][NW];
    const int b = blockIdx.x;
    const int tid = threadIdx.x;
    const float* base = xyz + (size_t)b * NPTS * 3;
    for (int i = tid; i < NPTS; i += TPB) {
        sx[i] = base[i * 3 + 0];
        sy[i] = base[i * 3 + 1];
        sz[i] = base[i * 3 + 2];
    }
    __syncthreads();
    float px[PPT], py[PPT], pz[PPT], dist[PPT];
#pragma unroll
    for (int k = 0; k < PPT; k++) {
        int p = tid + k * TPB;
        px[k] = sx[p]; py[k] = sy[p]; pz[k] = sz[p];
        dist[k] = 1e10f;
    }
    int far = 0;
    int myfar = 0;
    const int lane = tid & 63, wid = tid >> 6;
    for (int it = 0; it < NPOINT; it++) {
        if (tid == it) myfar = far;          // latch entering-far for the final write
        float fx = sx[far], fy = sy[far], fz = sz[far];
        float bv = -1.0f; int bi = 0;
#pragma unroll
        for (int k = 0; k < PPT; k++) {
            float d = sq3(px[k] - fx, py[k] - fy, pz[k] - fz);
            float nd = fminf(dist[k], d);
            dist[k] = nd;
            if (nd > bv) { bv = nd; bi = tid + k * TPB; }   // strict > keeps smallest k
        }
        unsigned long long P = ((unsigned long long)__float_as_uint(bv) << 32)
                             | (unsigned long long)(~(unsigned)bi & 0xFFFFFFFFull);
        P = dpp_wave_max_u64(P);
        int bufi = it & 1;
        if (lane == 63) slot[bufi][wid] = P;
        __syncthreads();
        // log-tree: all slot loads issued upfront, then pairwise max
        unsigned long long v[NW];
#pragma unroll
        for (int w = 0; w < NW; w++) v[w] = slot[bufi][w];
#pragma unroll
        for (int st = NW / 2; st >= 1; st >>= 1)
#pragma unroll
            for (int w = 0; w < st; w++) v[w] = u64max(v[w], v[w + st]);
        far = (int)(~(unsigned)(v[0] & 0xFFFFFFFFull));
    }
    if (tid < NPOINT) {
        float fx = sx[myfar], fy = sy[myfar], fz = sz[myfar];
        newxyz[((size_t)b * NPOINT + tid) * 3 + 0] = fx;
        newxyz[((size_t)b * NPOINT + tid) * 3 + 1] = fy;
        newxyz[((size_t)b * NPOINT + tid) * 3 + 2] = fz;
        if (out_t) {
            out_t[0 * ts + b * NPOINT + tid] = fx;
            out_t[1 * ts + b * NPOINT + tid] = fy;
            out_t[2 * ts + b * NPOINT + tid] = fz;
        }
    }
}

// ---------------- ball query body: one wave per center, ballot rounds ----------------
template<int NS>
__device__ __forceinline__ void bq_body(const float* __restrict__ pts, int n,
                                        const float* __restrict__ centers, int S,
                                        float r2, int* __restrict__ outidx,
                                        int wave, int lane) {
    int b = wave / S, s = wave % S;
    const float* c = centers + ((size_t)b * S + s) * 3;
    float cx = c[0], cy = c[1], cz = c[2];
    const float* pb = pts + (size_t)b * n * 3;
    int* out = outidx + ((size_t)b * S + s) * NS;
    int total = 0, first = -1;
    int rounds = n >> 6;
    for (int r = 0; r < rounds; r++) {
        int p = (r << 6) + lane;
        float dx = pb[p * 3 + 0] - cx, dy = pb[p * 3 + 1] - cy, dz = pb[p * 3 + 2] - cz;
        float d = sq3(dx, dy, dz);
        bool pred = (d <= r2);
        unsigned long long mask = __ballot(pred);
        if (first < 0 && mask) first = (r << 6) + (__ffsll(mask) - 1);
        if (pred) {
            int rank = total + __popcll(mask & ((1ull << lane) - 1ull));
            if (rank < NS) out[rank] = p;
        }
        total += __popcll(mask);
        if (total >= NS) break;
    }
    for (int j = total + lane; j < NS; j += 64) out[j] = first;
}

// generic weight -> bf16 hi/lo B-fragment conversion (one uint4 per thread)
__device__ __forceinline__ void wconv_one(const float* __restrict__ W, float* __restrict__ OF,
                                          int NT, int KT, int N, int t) {
    int L = t & 63;
    int rest = t >> 6;                       // (hl*KT + kt)*NT + nt
    int nt = rest & (NT - 1);
    int hk = rest / NT;
    int kt = hk % KT, hl = hk / KT;
    int k0 = kt * 32 + (L >> 4) * 8;
    int n  = nt * 16 + (L & 15);
    unsigned o[4];
#pragma unroll
    for (int e = 0; e < 4; e++) {
        float va = W[(size_t)(k0 + 2 * e + 0) * N + n];
        float vb = W[(size_t)(k0 + 2 * e + 1) * N + n];
        unsigned short ha, la, hb, lb;
        bf16split(va, ha, la);
        bf16split(vb, hb, lb);
        o[e] = hl ? ((unsigned)la | ((unsigned)lb << 16))
                  : ((unsigned)ha | ((unsigned)hb << 16));
    }
    ((uint4*)OF)[t] = make_uint4(o[0], o[1], o[2], o[3]);
}

// ---------------- fused: fps2 single-wave (blocks 0..15) + ballquery1 (16..1039)
// ---------------- + weight MFMA-fragment conversion (blocks 1040..1077) ----------------
// Weight frag layout (B-operand of mfma_f32_16x16x32_bf16, verified family m89/m91):
//   lane L holds B[k = kt*32 + 8*(L>>4) + e][n = nt*16 + (L&15)], e=0..7 packed 2-per-dword.
//   flat frag index t = ((hl*KT + kt)*NT + nt)*64 + L, 16B per t. hl: 0=hi bf16, 1=lo bf16.
__global__ __launch_bounds__(512) void bq1_fps2_kernel(const float* __restrict__ points,
                                                       const float* __restrict__ l1x,
                                                       float* __restrict__ l2x,
                                                       float* __restrict__ x3t,
                                                       int* __restrict__ idx1,
                                                       float r2a,
                                                       const float* __restrict__ w21,
                                                       const float* __restrict__ w22,
                                                       const float* __restrict__ w11s,
                                                       const float* __restrict__ w12s,
                                                       const float* __restrict__ w20s,
                                                       float* __restrict__ w21f,
                                                       float* __restrict__ w22f,
                                                       float* __restrict__ w11f,
                                                       float* __restrict__ w12f,
                                                       float* __restrict__ w20f) {
    __shared__ float sx[512], sy[512], sz[512];
    const int tid = threadIdx.x;
    const int lane = tid & 63, wid = tid >> 6;
    if (blockIdx.x < 16) {
        if (wid != 0) return;    // single-wave fps2; no barriers in this path
        const int b = blockIdx.x;
        const float* base = l1x + (size_t)b * 512 * 3;
        for (int i = lane; i < 512; i += 64) {
            sx[i] = base[i * 3 + 0];
            sy[i] = base[i * 3 + 1];
            sz[i] = base[i * 3 + 2];
        }
        float px[8], py[8], pz[8], dist[8];
#pragma unroll
        for (int k = 0; k < 8; k++) {
            int p = lane + k * 64;
            px[k] = sx[p]; py[k] = sy[p]; pz[k] = sz[p];
            dist[k] = 1e10f;
        }
        int far = 0, myfar0 = 0, myfar1 = 0;
        for (int it = 0; it < 128; it++) {
            if (lane == it) myfar0 = far;
            if (lane == it - 64) myfar1 = far;
            float fx = sx[far], fy = sy[far], fz = sz[far];
            float bv = -1.0f; int bi = 0;
#pragma unroll
            for (int k = 0; k < 8; k++) {
                float d = sq3(px[k] - fx, py[k] - fy, pz[k] - fz);
                float nd = fminf(dist[k], d);
                dist[k] = nd;
                if (nd > bv) { bv = nd; bi = lane + k * 64; }
            }
            unsigned long long P = ((unsigned long long)__float_as_uint(bv) << 32)
                                 | (unsigned long long)(~(unsigned)bi & 0xFFFFFFFFull);
            P = dpp_wave_max_u64(P);
            unsigned lo = (unsigned)__builtin_amdgcn_readlane((int)(unsigned)P, 63);
            far = (int)(~lo);          // idx was stored as ~idx in low 32
        }
        {
            int s0 = lane, s1 = lane + 64;
            float a = sx[myfar0], c1 = sy[myfar0], c2 = sz[myfar0];
            l2x[((size_t)b * 128 + s0) * 3 + 0] = a;
            l2x[((size_t)b * 128 + s0) * 3 + 1] = c1;
            l2x[((size_t)b * 128 + s0) * 3 + 2] = c2;
            x3t[0 * 2048 + b * 128 + s0] = a;
            x3t[1 * 2048 + b * 128 + s0] = c1;
            x3t[2 * 2048 + b * 128 + s0] = c2;
            float d = sx[myfar1], e = sy[myfar1], f = sz[myfar1];
            l2x[((size_t)b * 128 + s1) * 3 + 0] = d;
            l2x[((size_t)b * 128 + s1) * 3 + 1] = e;
            l2x[((size_t)b * 128 + s1) * 3 + 2] = f;
            x3t[0 * 2048 + b * 128 + s1] = d;
            x3t[1 * 2048 + b * 128 + s1] = e;
            x3t[2 * 2048 + b * 128 + s1] = f;
        }
    } else if (blockIdx.x < 1040) {
        int wave = (blockIdx.x - 16) * 8 + wid;   // 1024 blocks x 8 waves = 8192
        bq_body<32>(points, 4096, l1x, 512, r2a, idx1, wave, lane);
    } else {
        // weight -> bf16 hi/lo MFMA-fragment conversion. 38 blocks x 512 thr = 19456
        int gt = (blockIdx.x - 1040) * 512 + tid;
        if (gt < 4096)       wconv_one(w21,        w21f, 8,  4, 128, gt);
        else if (gt < 12288) wconv_one(w22,        w22f, 16, 4, 256, gt - 4096);
        else if (gt < 13312) wconv_one(w11s,       w11f, 4,  2, 64,  gt - 12288);
        else if (gt < 15360) wconv_one(w12s,       w12f, 8,  2, 128, gt - 13312);
        else                 wconv_one(w20s + 384, w20f, 8,  4, 128, gt - 15360);  // w20 rows 3..130
    }
}

// ---------------- fused: ballquery2 (blocks 0..2047) + SA1 MFMA (blocks 2048..6143) ----------------
// SA1: per 1-wave block, 2 centers x 32 nbrs = M=64 rows. Layer1 (3->64) fp32 scalar,
// split to bf16 hi/lo in LDS [64 rows][64 ch] stride 72 shorts (144B, 16B-aligned frags).
// Layers 2 (64->64, K=64) and 3 (64->128, K=64): MFMA bf16x3, then per-center max-pool.
__global__ __launch_bounds__(64, 2) void sa1_bq2_kernel(const float* __restrict__ xyz, const float* __restrict__ l1x,
                                                 const int* __restrict__ idx1,
                                                 const float* __restrict__ l2x, int* __restrict__ idx2, float r2b,
                                                 const float* __restrict__ W1, const float* __restrict__ B1,
                                                 const float* __restrict__ W2f, const float* __restrict__ B2,
                                                 const float* __restrict__ W3f, const float* __restrict__ B3,
                                                 float* __restrict__ l1f) {
    __shared__ short hsh[64 * 72];   // bf16 hi, [row][ch]
    __shared__ short hsl[64 * 72];   // bf16 lo
    int lane = threadIdx.x;
    if (blockIdx.x < 2048) {
        bq_body<64>(l1x, 512, l2x, 128, r2b, idx2, blockIdx.x, lane);
        return;
    }
    int blk = blockIdx.x - 2048;
    int b = blk >> 8;
    int ct = lane >> 5, nn = lane & 31;
    int s = ((blk & 255) << 1) | ct;
    int center = b * 512 + s;
    int c0 = b * 512 + ((blk & 255) << 1);       // pooled-output centers
    int ii = idx1[center * 32 + nn];
    float px = xyz[((size_t)b * NN + ii) * 3 + 0] - l1x[(size_t)center * 3 + 0];
    float py = xyz[((size_t)b * NN + ii) * 3 + 1] - l1x[(size_t)center * 3 + 1];
    float pz = xyz[((size_t)b * NN + ii) * 3 + 2] - l1x[(size_t)center * 3 + 2];
    // layer1: 3->64, relu, split -> LDS row-major (row = lane)
#pragma unroll
    for (int c2 = 0; c2 < 32; c2++) {
        int ca = 2 * c2, cb = 2 * c2 + 1;
        float v0 = fmaxf(B1[ca] + px * W1[ca] + py * W1[64 + ca] + pz * W1[128 + ca], 0.0f);
        float v1 = fmaxf(B1[cb] + px * W1[cb] + py * W1[64 + cb] + pz * W1[128 + cb], 0.0f);
        unsigned short h0, l0, h1, l1;
        bf16split(v0, h0, l0);
        bf16split(v1, h1, l1);
        int base = lane * 72 + ca;
        *(unsigned*)(&hsh[base]) = (unsigned)h0 | ((unsigned)h1 << 16);
        *(unsigned*)(&hsl[base]) = (unsigned)l0 | ((unsigned)l1 << 16);
    }
    __syncthreads();
    // ---- layer2: [64x64] = relu([64x64] x w11 + b11), MFMA bf16x3 ----
    {
        fx4 acc[4][4];
#pragma unroll
        for (int mt = 0; mt < 4; mt++)
#pragma unroll
            for (int nt = 0; nt < 4; nt++) {
                float bn = B2[nt * 16 + (lane & 15)];
                acc[mt][nt] = (fx4){bn, bn, bn, bn};
            }
        const bfrag8* w2v = (const bfrag8*)W2f;
#pragma unroll
        for (int kt = 0; kt < 2; kt++) {
            bfrag8 ah[4], al[4];
#pragma unroll
            for (int mt = 0; mt < 4; mt++) {
                int idx = (mt * 16 + (lane & 15)) * 72 + kt * 32 + (lane >> 4) * 8;
                ah[mt] = *(const bfrag8*)(&hsh[idx]);
                al[mt] = *(const bfrag8*)(&hsl[idx]);
            }
#pragma unroll
            for (int nt = 0; nt < 4; nt++) {
                bfrag8 bh = w2v[(size_t)((0 + kt) * 4 + nt) * 64 + lane];
                bfrag8 bl = w2v[(size_t)((2 + kt) * 4 + nt) * 64 + lane];
#pragma unroll
                for (int mt = 0; mt < 4; mt++) {
                    acc[mt][nt] = mfma16(ah[mt], bh, acc[mt][nt]);
                    acc[mt][nt] = mfma16(ah[mt], bl, acc[mt][nt]);
                    acc[mt][nt] = mfma16(al[mt], bh, acc[mt][nt]);
                }
            }
        }
        __syncthreads();
        // relu + split back to LDS (C/D map: m = mt*16 + (lane>>4)*4 + r, n = nt*16 + (lane&15))
#pragma unroll
        for (int mt = 0; mt < 4; mt++)
#pragma unroll
            for (int nt = 0; nt < 4; nt++)
#pragma unroll
                for (int r = 0; r < 4; r++) {
                    float v = fmaxf(acc[mt][nt][r], 0.0f);
                    int m = mt * 16 + (lane >> 4) * 4 + r;
                    int n = nt * 16 + (lane & 15);
                    unsigned short hb, lb;
                    bf16split(v, hb, lb);
                    hsh[m * 72 + n] = (short)hb;
                    hsl[m * 72 + n] = (short)lb;
                }
        __syncthreads();
    }
    // ---- layer3: [64x128] = relu([64x64] x w12 + b12), MFMA bf16x3, max-pool per center ----
    const bfrag8* w3v = (const bfrag8*)W3f;
#pragma unroll 1
    for (int pass = 0; pass < 2; pass++) {
        int nbase = pass * 4;
        fx4 acc[4][4];
#pragma unroll
        for (int mt = 0; mt < 4; mt++)
#pragma unroll
            for (int nt = 0; nt < 4; nt++) {
                float bn = B3[(nbase + nt) * 16 + (lane & 15)];
                acc[mt][nt] = (fx4){bn, bn, bn, bn};
            }
#pragma unroll
        for (int kt = 0; kt < 2; kt++) {
            bfrag8 ah[4], al[4];
#pragma unroll
            for (int mt = 0; mt < 4; mt++) {
                int idx = (mt * 16 + (lane & 15)) * 72 + kt * 32 + (lane >> 4) * 8;
                ah[mt] = *(const bfrag8*)(&hsh[idx]);
                al[mt] = *(const bfrag8*)(&hsl[idx]);
            }
#pragma unroll
            for (int nt = 0; nt < 4; nt++) {
                bfrag8 bh = w3v[(size_t)((0 + kt) * 8 + nbase + nt) * 64 + lane];
                bfrag8 bl = w3v[(size_t)((2 + kt) * 8 + nbase + nt) * 64 + lane];
#pragma unroll
                for (int mt = 0; mt < 4; mt++) {
                    acc[mt][nt] = mfma16(ah[mt], bh, acc[mt][nt]);
                    acc[mt][nt] = mfma16(ah[mt], bl, acc[mt][nt]);
                    acc[mt][nt] = mfma16(al[mt], bh, acc[mt][nt]);
                }
            }
        }
        // pool: rows 0..31 -> center c0, rows 32..63 -> c0+1. relu(max) = max(max,0).
#pragma unroll
        for (int nt = 0; nt < 4; nt++) {
            float mv0 = 0.0f, mv1 = 0.0f;
#pragma unroll
            for (int r = 0; r < 4; r++) {
                mv0 = fmaxf(mv0, fmaxf(acc[0][nt][r], acc[1][nt][r]));
                mv1 = fmaxf(mv1, fmaxf(acc[2][nt][r], acc[3][nt][r]));
            }
            mv0 = fmaxf(mv0, __shfl_xor(mv0, 16));
            mv0 = fmaxf(mv0, __shfl_xor(mv0, 32));
            mv1 = fmaxf(mv1, __shfl_xor(mv1, 16));
            mv1 = fmaxf(mv1, __shfl_xor(mv1, 32));
            int n = (nbase + nt) * 16 + (lane & 15);
            if (lane < 16)      l1f[(size_t)c0 * 128 + n] = mv0;
            else if (lane < 32) l1f[(size_t)(c0 + 1) * 128 + n] = mv1;
        }
    }
}

// ---------------- SA2 MLP: 131->128->128->256, max over 64 nbrs — ALL layers MFMA ----------------
// Layer 1 K=131 = 3 (xyz, rank-3 C-init correction) + 128 (features, MFMA w20f).
// Activations in LDS as [64 nbr][128 ch] bf16 x {hi,lo}, row stride 136 shorts (272B).
// Frag maps (m89/m91 family): A: (m=L&15, k=8*(L>>4)+e); B: (n=L&15, k=8*(L>>4)+e);
//                             C/D: (n=L&15, m=4*(L>>4)+r).
__global__ __launch_bounds__(256, 4) void sa2_kernel(const float* __restrict__ l1x, const float* __restrict__ l2x,
                                                  const float* __restrict__ l1f, const int* __restrict__ idx2,
                                                  const float* __restrict__ W1, const float* __restrict__ B1,
                                                  const float* __restrict__ w20f,
                                                  const float* __restrict__ w21f, const float* __restrict__ B2,
                                                  const float* __restrict__ w22f, const float* __restrict__ B3,
                                                  float* __restrict__ x3t) {
    __shared__ short hsh[64 * 136];   // bf16 hi, [nbr][ch], stride 136 shorts
    __shared__ short hsl[64 * 136];   // bf16 lo
    __shared__ float sxyz[64 * 4];    // centered xyz per row (stride 4)
    int tid = threadIdx.x;
    int w = __builtin_amdgcn_readfirstlane(tid >> 6);   // 0..3, wave-uniform -> SGPR
    int lane = tid & 63;
    int b = blockIdx.x >> 7, s = blockIdx.x & 127;
    int center = b * 128 + s;
    int ii = idx2[center * 64 + lane];
    float cx = l2x[(size_t)center * 3 + 0], cy = l2x[(size_t)center * 3 + 1], cz = l2x[(size_t)center * 3 + 2];
    const float* pr = l1x + ((size_t)b * 512 + ii) * 3;
    float px = pr[0] - cx, py = pr[1] - cy, pz = pr[2] - cz;
    if (w == 0) {
        sxyz[lane * 4 + 0] = px;
        sxyz[lane * 4 + 1] = py;
        sxyz[lane * 4 + 2] = pz;
    }
    // stage gathered features: wave w handles ch 32w..32w+31
    {
        const float4* frow = (const float4*)(l1f + ((size_t)b * 512 + ii) * 128);
#pragma unroll
        for (int j = 0; j < 8; j++) {
            float4 f = frow[w * 8 + j];
            unsigned short h0, l0, h1, l1, h2, l2, h3, l3;
            bf16split(f.x, h0, l0);
            bf16split(f.y, h1, l1);
            bf16split(f.z, h2, l2);
            bf16split(f.w, h3, l3);
            int cb = lane * 136 + w * 32 + 4 * j;
            *(unsigned*)(&hsh[cb + 0]) = (unsigned)h0 | ((unsigned)h1 << 16);
            *(unsigned*)(&hsh[cb + 2]) = (unsigned)h2 | ((unsigned)h3 << 16);
            *(unsigned*)(&hsl[cb + 0]) = (unsigned)l0 | ((unsigned)l1 << 16);
            *(unsigned*)(&hsl[cb + 2]) = (unsigned)l2 | ((unsigned)l3 << 16);
        }
    }
    __syncthreads();
    // ---- layer1: [64x128] = relu(feat[64x128] x w20[3:] + xyz x w20[0:3] + b20), MFMA bf16x3 ----
    {
        fx4 acc[4][2];
        float w0n[2], w1n[2], w2n[2];
#pragma unroll
        for (int nt = 0; nt < 2; nt++) {
            int n = (2 * w + nt) * 16 + (lane & 15);
            float bn = B1[n];
            acc[0][nt] = (fx4){bn, bn, bn, bn};
            acc[1][nt] = acc[0][nt]; acc[2][nt] = acc[0][nt]; acc[3][nt] = acc[0][nt];
            w0n[nt] = W1[n]; w1n[nt] = W1[128 + n]; w2n[nt] = W1[256 + n];
        }
        // xyz rank-3 correction into C fragments
#pragma unroll
        for (int mt = 0; mt < 4; mt++)
#pragma unroll
            for (int r = 0; r < 4; r++) {
                int m = mt * 16 + (lane >> 4) * 4 + r;
                float mx = sxyz[m * 4 + 0], my = sxyz[m * 4 + 1], mz = sxyz[m * 4 + 2];
#pragma unroll
                for (int nt = 0; nt < 2; nt++)
                    acc[mt][nt][r] += mx * w0n[nt] + my * w1n[nt] + mz * w2n[nt];
            }
#pragma unroll
        for (int kt = 0; kt < 4; kt++) {
            bfrag8 ah[4], al[4];
#pragma unroll
            for (int mt = 0; mt < 4; mt++) {
                int idx = (mt * 16 + (lane & 15)) * 136 + kt * 32 + (lane >> 4) * 8;
                ah[mt] = *(const bfrag8*)(&hsh[idx]);
                al[mt] = *(const bfrag8*)(&hsl[idx]);
            }
#pragma unroll
            for (int nt = 0; nt < 2; nt++) {
                int ng = 2 * w + nt;
                bfrag8 bh = ((const bfrag8*)w20f)[(size_t)((0 + kt) * 8 + ng) * 64 + lane];
                bfrag8 bl = ((const bfrag8*)w20f)[(size_t)((4 + kt) * 8 + ng) * 64 + lane];
#pragma unroll
                for (int mt = 0; mt < 4; mt++) {
                    acc[mt][nt] = mfma16(ah[mt], bh, acc[mt][nt]);
                    acc[mt][nt] = mfma16(ah[mt], bl, acc[mt][nt]);
                    acc[mt][nt] = mfma16(al[mt], bh, acc[mt][nt]);
                }
            }
        }
        __syncthreads();   // all waves done reading feat -> safe to overwrite
#pragma unroll
        for (int mt = 0; mt < 4; mt++)
#pragma unroll
            for (int nt = 0; nt < 2; nt++)
#pragma unroll
                for (int r = 0; r < 4; r++) {
                    float v = fmaxf(acc[mt][nt][r], 0.0f);
                    int m = mt * 16 + (lane >> 4) * 4 + r;
                    int n = (2 * w + nt) * 16 + (lane & 15);
                    unsigned short hb, lb;
                    bf16split(v, hb, lb);
                    hsh[m * 136 + n] = (short)hb;
                    hsl[m * 136 + n] = (short)lb;
                }
        __syncthreads();
    }
    // ---- layer2: [64x128] = relu([64x128] x w21 + b21), MFMA bf16x3 ----
    {
        fx4 acc[4][2];
#pragma unroll
        for (int mt = 0; mt < 4; mt++)
#pragma unroll
            for (int nt = 0; nt < 2; nt++) {
                float bn = B2[(2 * w + nt) * 16 + (lane & 15)];
                acc[mt][nt] = (fx4){bn, bn, bn, bn};
            }
#pragma unroll
        for (int kt = 0; kt < 4; kt++) {
            bfrag8 ah[4], al[4];
#pragma unroll
            for (int mt = 0; mt < 4; mt++) {
                int idx = (mt * 16 + (lane & 15)) * 136 + kt * 32 + (lane >> 4) * 8;
                ah[mt] = *(const bfrag8*)(&hsh[idx]);
                al[mt] = *(const bfrag8*)(&hsl[idx]);
            }
#pragma unroll
            for (int nt = 0; nt < 2; nt++) {
                int ng = 2 * w + nt;
                bfrag8 bh = ((const bfrag8*)w21f)[(size_t)((0 + kt) * 8 + ng) * 64 + lane];
                bfrag8 bl = ((const bfrag8*)w21f)[(size_t)((4 + kt) * 8 + ng) * 64 + lane];
#pragma unroll
                for (int mt = 0; mt < 4; mt++) {
                    acc[mt][nt] = mfma16(ah[mt], bh, acc[mt][nt]);
                    acc[mt][nt] = mfma16(ah[mt], bl, acc[mt][nt]);
                    acc[mt][nt] = mfma16(al[mt], bh, acc[mt][nt]);
                }
            }
        }
        __syncthreads();   // all waves done reading layer1 acts -> safe to overwrite
#pragma unroll
        for (int mt = 0; mt < 4; mt++)
#pragma unroll
            for (int nt = 0; nt < 2; nt++)
#pragma unroll
                for (int r = 0; r < 4; r++) {
                    float v = fmaxf(acc[mt][nt][r], 0.0f);
                    int m = mt * 16 + (lane >> 4) * 4 + r;
                    int n = (2 * w + nt) * 16 + (lane & 15);
                    unsigned short hb, lb;
                    bf16split(v, hb, lb);
                    hsh[m * 136 + n] = (short)hb;
                    hsl[m * 136 + n] = (short)lb;
                }
        __syncthreads();
    }
    // ---- layer3: [64x256] = relu([64x128] x w22 + b22), MFMA bf16x3, then max over 64 nbrs ----
#pragma unroll 1
    for (int pass = 0; pass < 2; pass++) {
        int nb = w * 4 + pass * 2;            // global n-tile base (of 16)
        fx4 acc[4][2];
#pragma unroll
        for (int mt = 0; mt < 4; mt++)
#pragma unroll
            for (int nt = 0; nt < 2; nt++) {
                float bn = B3[(nb + nt) * 16 + (lane & 15)];
                acc[mt][nt] = (fx4){bn, bn, bn, bn};
            }
#pragma unroll
        for (int kt = 0; kt < 4; kt++) {
            bfrag8 ah[4], al[4];
#pragma unroll
            for (int mt = 0; mt < 4; mt++) {
                int idx = (mt * 16 + (lane & 15)) * 136 + kt * 32 + (lane >> 4) * 8;
                ah[mt] = *(const bfrag8*)(&hsh[idx]);
                al[mt] = *(const bfrag8*)(&hsl[idx]);
            }
#pragma unroll
            for (int nt = 0; nt < 2; nt++) {
                bfrag8 bh = ((const bfrag8*)w22f)[(size_t)((0 + kt) * 16 + (nb + nt)) * 64 + lane];
                bfrag8 bl = ((const bfrag8*)w22f)[(size_t)((4 + kt) * 16 + (nb + nt)) * 64 + lane];
#pragma unroll
                for (int mt = 0; mt < 4; mt++) {
                    acc[mt][nt] = mfma16(ah[mt], bh, acc[mt][nt]);
                    acc[mt][nt] = mfma16(ah[mt], bl, acc[mt][nt]);
                    acc[mt][nt] = mfma16(al[mt], bh, acc[mt][nt]);
                }
            }
        }
#pragma unroll
        for (int nt = 0; nt < 2; nt++) {
            float mv = 0.0f;   // relu(max) == max(max, 0)
#pragma unroll
            for (int mt = 0; mt < 4; mt++)
#pragma unroll
                for (int r = 0; r < 4; r++)
                    mv = fmaxf(mv, acc[mt][nt][r]);
            mv = fmaxf(mv, __shfl_xor(mv, 16));
            mv = fmaxf(mv, __shfl_xor(mv, 32));
            if (lane < 16)
                x3t[(size_t)(3 + (nb + nt) * 16 + lane) * 2048 + center] = mv;
        }
    }
}

// ---------------- transposed GEMM body (packed fp32, used by gemm1) ----------------
template<int K, int COUT, int CPT>
__device__ __forceinline__ void gemm1_body_bf16out(const float* __restrict__ in_t,
                                                   const float* __restrict__ W,
                                                   const float* __restrict__ bias,
                                                   unsigned short* __restrict__ oh,
                                                   unsigned short* __restrict__ ol,
                                                   int bid, int lane) {
    int rw = bid & 31, cg = bid >> 5;
    int row = rw * 64 + lane;
    int cbase = cg * CPT;
    v2f acc[CPT / 2];
    const v2f* bv = (const v2f*)(bias + cbase);
#pragma unroll
    for (int j = 0; j < CPT / 2; j++) acc[j] = bv[j];
    for (int k = 0; k < K; k++) {
        float xk = in_t[(size_t)k * 2048 + row];
        v2f xk2 = {xk, xk};
        const v2f* wr = (const v2f*)(W + (size_t)k * COUT + cbase);
#pragma unroll
        for (int j = 0; j < CPT / 2; j++) acc[j] = pkfma(xk2, wr[j], acc[j]);
    }
    // relu + bf16 hi/lo split; 8 consecutive cols at fixed row -> one uint4 per plane
    unsigned ho[4], lo[4];
#pragma unroll
    for (int j = 0; j < CPT / 2; j++) {
        float va = fmaxf(acc[j].x, 0.0f);
        float vb = fmaxf(acc[j].y, 0.0f);
        unsigned short ha, la, hb, lb;
        bf16split(va, ha, la);
        bf16split(vb, hb, lb);
        ho[j] = (unsigned)ha | ((unsigned)hb << 16);
        lo[j] = (unsigned)la | ((unsigned)lb << 16);
    }
    size_t idx = ((size_t)row * COUT + cbase) >> 3;   // uint4 index
    ((uint4*)oh)[idx] = make_uint4(ho[0], ho[1], ho[2], ho[3]);
    ((uint4*)ol)[idx] = make_uint4(lo[0], lo[1], lo[2], lo[3]);
}

// gemm1 CPT=8 (blocks 0..1023) + zero-init of g (1024..1279) + w31/w32 frag conversion (1280..3839)
// Conversion writes into l1f alias — safe: sa2 (last l1f reader) completed in a prior dispatch.
__global__ __launch_bounds__(64, 4) void gemm1_zerog_kernel(const float* __restrict__ in_t,
                                                            const float* __restrict__ W,
                                                            const float* __restrict__ bias,
                                                            unsigned short* __restrict__ h1h,
                                                            unsigned short* __restrict__ h1l,
                                                            float* __restrict__ g,
                                                            const float* __restrict__ w31,
                                                            const float* __restrict__ w32,
                                                            float* __restrict__ w31f,
                                                            float* __restrict__ w32f) {
    if (blockIdx.x < 1024) {
        gemm1_body_bf16out<259, 256, 8>(in_t, W, bias, h1h, h1l, blockIdx.x, threadIdx.x);
    } else if (blockIdx.x < 1280) {
        g[(blockIdx.x - 1024) * 64 + threadIdx.x] = 0.0f;
    } else {
        int gt = (blockIdx.x - 1280) * 64 + threadIdx.x;
        if (gt < 32768) wconv_one(w31, w31f, 32, 8,  512,  gt);
        else            wconv_one(w32, w32f, 64, 16, 1024, gt - 32768);
    }
}

// ---------------- MFMA GEMM on bf16 hi/lo planes (A from global, no LDS) ----------------
// A-frag: lane L loads 16B at row (mbase + mt*16 + (L&15)), k = kt*32 + (L>>4)*8 — the
// row-major bf16 plane IS the fragment layout. B from pre-converted frags. bf16x3.
template<int K, int NT_TOT, bool MAXOUT>
__global__ __launch_bounds__(64, 4) void gemm_mfma_kernel(const unsigned short* __restrict__ Ah,
                                                          const unsigned short* __restrict__ Al,
                                                          const float* __restrict__ Wf,
                                                          const float* __restrict__ bias,
                                                          unsigned short* __restrict__ Oh,
                                                          unsigned short* __restrict__ Ol,
                                                          float* __restrict__ g) {
    constexpr int KT = K / 32;
    constexpr int NCOL = NT_TOT * 16;
    int lane = threadIdx.x;
    int mtile = blockIdx.x & 31, bn = blockIdx.x >> 5;
    int mbase = mtile * 64;
    int nb4 = bn * 4;                       // base nt16 group (4 per wave = 64 cols)
    const bfrag8* wv = (const bfrag8*)Wf;
    fx4 acc[4][4];
#pragma unroll
    for (int mt = 0; mt < 4; mt++)
#pragma unroll
        for (int j = 0; j < 4; j++) {
            float bnv = bias[(nb4 + j) * 16 + (lane & 15)];
            acc[mt][j] = (fx4){bnv, bnv, bnv, bnv};
        }
#pragma unroll 1
    for (int kt = 0; kt < KT; kt++) {
        bfrag8 ah[4], al[4];
#pragma unroll
        for (int mt = 0; mt < 4; mt++) {
            size_t off = (size_t)(mbase + mt * 16 + (lane & 15)) * K + kt * 32 + (lane >> 4) * 8;
            ah[mt] = *(const bfrag8*)(Ah + off);
            al[mt] = *(const bfrag8*)(Al + off);
        }
#pragma unroll
        for (int j = 0; j < 4; j++) {
            bfrag8 bh = wv[(size_t)((0 * KT + kt) * NT_TOT + nb4 + j) * 64 + lane];
            bfrag8 bl = wv[(size_t)((1 * KT + kt) * NT_TOT + nb4 + j) * 64 + lane];
#pragma unroll
            for (int mt = 0; mt < 4; mt++) {
                acc[mt][j] = mfma16(ah[mt], bh, acc[mt][j]);
                acc[mt][j] = mfma16(ah[mt], bl, acc[mt][j]);
                acc[mt][j] = mfma16(al[mt], bh, acc[mt][j]);
            }
        }
    }
    if (MAXOUT) {
        int b = mbase >> 7;                 // 64-row tile lies in one 128-row batch
#pragma unroll
        for (int j = 0; j < 4; j++) {
            float mv = 0.0f;                // relu(max) == max(max, 0)
#pragma unroll
            for (int mt = 0; mt < 4; mt++)
#pragma unroll
                for (int r = 0; r < 4; r++)
                    mv = fmaxf(mv, acc[mt][j][r]);
            mv = fmaxf(mv, __shfl_xor(mv, 16));
            mv = fmaxf(mv, __shfl_xor(mv, 32));
            if (lane < 16)
                atomicMax((int*)(g + (size_t)b * 1024 + (nb4 + j) * 16 + lane), __float_as_int(mv));
        }
    } else {
#pragma unroll
        for (int mt = 0; mt < 4; mt++)
#pragma unroll
            for (int j = 0; j < 4; j++)
#pragma unroll
                for (int r = 0; r < 4; r++) {
                    float v = fmaxf(acc[mt][j][r], 0.0f);
                    int m = mbase + mt * 16 + (lane >> 4) * 4 + r;
                    int n = (nb4 + j) * 16 + (lane & 15);
                    unsigned short hb, lb;
                    bf16split(v, hb, lb);
                    Oh[(size_t)m * NCOL + n] = hb;
                    Ol[(size_t)m * NCOL + n] = lb;
                }
    }
}

// ---------------- FC heads ----------------
__global__ __launch_bounds__(512) void head_kernel(const float* __restrict__ g,
                                                   const float* __restrict__ lw1, const float* __restrict__ lb1,
                                                   const float* __restrict__ lw2, const float* __restrict__ lb2,
                                                   const float* __restrict__ fw1, const float* __restrict__ fb1,
                                                   const float* __restrict__ fw2, const float* __restrict__ fb2,
                                                   const float* __restrict__ pm, const float* __restrict__ ps,
                                                   const float* __restrict__ rm, const float* __restrict__ rs,
                                                   float* __restrict__ out) {
    __shared__ float gl[1024], a1[256], f1[512];
    int b = blockIdx.x, t = threadIdx.x;
    for (int i = t; i < 1024; i += 512) gl[i] = g[b * 1024 + i];
    __syncthreads();
    {
        float acc = fb1[t];
        for (int k = 0; k < 1024; k++) acc += gl[k] * fw1[k * 512 + t];
        f1[t] = fmaxf(acc, 0.0f);
    }
    if (t < 256) {
        float acc = lb1[t];
        for (int k = 0; k < 1024; k++) acc += gl[k] * lw1[k * 256 + t];
        a1[t] = fmaxf(acc, 0.0f);
    }
    __syncthreads();
    if (t < 2) {
        float z = lb2[t];
        for (int k = 0; k < 256; k++) z += a1[k] * lw2[k * 2 + t];
        out[b * 20 + t] = 1.0f / (1.0f + expf(-z));
    } else if (t < 20) {
        int i = t - 2;
        float z = fb2[i];
        for (int k = 0; k < 512; k++) z += f1[k] * fw2[k * 18 + i];
        float sc, mn;
        if (i < 3)       { sc = ps[i];      mn = pm[i]; }
        else if (i < 9)  { sc = rs[i - 3];  mn = rm[i - 3]; }
        else if (i < 12) { sc = ps[i - 9];  mn = pm[i - 9]; }
        else             { sc = rs[i - 12]; mn = rm[i - 12]; }
        out[b * 20 + t] = z * sc + mn;
    }
}

static inline size_t align256(size_t x) { return (x + 255) & ~(size_t)255; }

extern "C" void kernel_launch(void* const* d_in, const int* in_sizes, int n_in,
                              void* d_out, int out_size, void* d_ws, size_t ws_size,
                              hipStream_t stream) {
    const float* points = (const float*)d_in[0];
    const float* w10 = (const float*)d_in[1];  const float* b10 = (const float*)d_in[2];
    const float* w11 = (const float*)d_in[3];  const float* b11 = (const float*)d_in[4];
    const float* w12 = (const float*)d_in[5];  const float* b12 = (const float*)d_in[6];
    const float* w20 = (const float*)d_in[7];  const float* b20 = (const float*)d_in[8];
    const float* w21 = (const float*)d_in[9];  const float* b21 = (const float*)d_in[10];
    const float* w22 = (const float*)d_in[11]; const float* b22 = (const float*)d_in[12];
    const float* w30 = (const float*)d_in[13]; const float* b30 = (const float*)d_in[14];
    const float* w31 = (const float*)d_in[15]; const float* b31 = (const float*)d_in[16];
    const float* w32 = (const float*)d_in[17]; const float* b32 = (const float*)d_in[18];
    const float* lw1 = (const float*)d_in[19]; const float* lb1 = (const float*)d_in[20];
    const float* lw2 = (const float*)d_in[21]; const float* lb2 = (const float*)d_in[22];
    const float* fw1 = (const float*)d_in[23]; const float* fb1 = (const float*)d_in[24];
    const float* fw2 = (const float*)d_in[25]; const float* fb2 = (const float*)d_in[26];
    const float* pm  = (const float*)d_in[27]; const float* ps  = (const float*)d_in[28];
    const float* rm  = (const float*)d_in[29]; const float* rs  = (const float*)d_in[30];
    float* out = (float*)d_out;

    char* p = (char*)d_ws;
    float* l1x  = (float*)p; p += align256((size_t)BB * 512 * 3 * 4);
    int*   idx1 = (int*)p;   p += align256((size_t)BB * 512 * 32 * 4);
    float* l1f  = (float*)p; p += align256((size_t)BB * 512 * 128 * 4);
    float* l2x  = (float*)p; p += align256((size_t)BB * 128 * 3 * 4);
    int*   idx2 = (int*)p;   p += align256((size_t)BB * 128 * 64 * 4);
    float* x3t  = (float*)p; p += align256((size_t)259 * 2048 * 4);
    float* h1t  = (float*)p; p += align256((size_t)256 * 2048 * 4);
    float* h2t  = (float*)p; p += align256((size_t)512 * 2048 * 4);
    float* g    = (float*)p; p += align256((size_t)BB * 1024 * 4);
    // SA weight fragments (304 KB) alias head of h1t: produced by bq1_fps2, consumed by
    // sa1_bq2/sa2; h1t's first overwrite (gemm1_zerog h1 planes) is stream-ordered after.
    float* w21f = h1t;                                   // 64 KB
    float* w22f = h1t + (size_t)16384;                   // 128 KB
    float* w11f = h1t + (size_t)49152;                   // 16 KB
    float* w12f = h1t + (size_t)53248;                   // 32 KB
    float* w20f = h1t + (size_t)61440;                   // 64 KB
    // h1/h2 as bf16 hi/lo planes in the SAME footprint as the old fp32 buffers.
    unsigned short* h1h = (unsigned short*)h1t;                       // 1 MB (2048x256)
    unsigned short* h1l = h1h + (size_t)2048 * 256;                   // 1 MB
    unsigned short* h2h = (unsigned short*)h2t;                       // 2 MB (2048x512)
    unsigned short* h2l = h2h + (size_t)2048 * 512;                   // 2 MB
    // gemm2/3 weight fragments (2.5 MB) alias l1f (4 MB): converted in gemm1_zerog,
    // which runs after sa2 (last l1f reader). Consumed by gemm2/gemm3.
    float* w31f = l1f;                                   // 512 KB
    float* w32f = l1f + (size_t)131072;                  // 2 MB

    const float R2A = (float)(0.2 * 0.2);
    const float R2B = (float)(0.4 * 0.4);

    fps_kernel<4096, 512, 512><<<BB, 512, 0, stream>>>(points, l1x, (float*)nullptr, 0);
    bq1_fps2_kernel<<<1078, 512, 0, stream>>>(points, l1x, l2x, x3t, idx1, R2A,
                                              w21, w22, w11, w12, w20,
                                              w21f, w22f, w11f, w12f, w20f);
    sa1_bq2_kernel<<<6144, 64, 0, stream>>>(points, l1x, idx1, l2x, idx2, R2B,
                                            w10, b10, w11f, b11, w12f, b12, l1f);
    sa2_kernel<<<2048, 256, 0, stream>>>(l1x, l2x, l1f, idx2, w20, b20,
                                         w20f, w21f, b21, w22f, b22, x3t);
    gemm1_zerog_kernel<<<3840, 64, 0, stream>>>(x3t, w30, b30, h1h, h1l, g, w31, w32, w31f, w32f);
    gemm_mfma_kernel<256, 32, false><<<256, 64, 0, stream>>>(h1h, h1l, w31f, b31, h2h, h2l, (float*)nullptr);
    gemm_mfma_kernel<512, 64, true><<<512, 64, 0, stream>>>(h2h, h2l, w32f, b32,
                                                            (unsigned short*)nullptr, (unsigned short*)nullptr, g);
    head_kernel<<<BB, 512, 0, stream>>>(g, lw1, lb1, lw2, lb2, fw1, fb1, fw2, fb2, pm, ps, rm, rs, out);
}